// Round 4
// baseline (197.624 us; speedup 1.0000x reference)
//
#include <hip/hip_runtime.h>
#include <hip/hip_bf16.h>

// EdgeDecoder: out[e] = relu(concat(zu[row[e]], zr[col[e]]) @ W1 + b1) @ W2 + b2
// R4: same two-pass factorization as R3 (proj_nodes MFMA -> Hu/Hr bf16 in
// d_ws; edge_pass gather+relu+dot), with latency-oriented tuning:
//   - edge_pass: 4 edges per quarter-wave (16 edges/wave/iter) -> 8 gather
//     dwordx4 in flight; int4 index loads (one per 4 edges); float4 output
//     stores. Discriminates latency-bound vs L3-service-bound.
//   - proj_nodes: 512-thread blocks (8 waves share the 64 KB W1 LDS tile,
//     2 blocks/CU = 16 waves/CU), full-tile store path unpredicated.

#define HDIM 128

typedef __attribute__((ext_vector_type(8))) __bf16 bf16x8;
typedef __attribute__((ext_vector_type(16))) float f32x16;

static __device__ __forceinline__ unsigned short bf16_bits(float x) {
  return __builtin_bit_cast(unsigned short, static_cast<__bf16>(x));
}

static __device__ __forceinline__ float bf2f(unsigned short u) {
  return __builtin_bit_cast(float, ((unsigned int)u) << 16);
}

static __device__ __forceinline__ bf16x8 cvt8(float4 a, float4 b) {
  bf16x8 r;
  r[0] = static_cast<__bf16>(a.x);
  r[1] = static_cast<__bf16>(a.y);
  r[2] = static_cast<__bf16>(a.z);
  r[3] = static_cast<__bf16>(a.w);
  r[4] = static_cast<__bf16>(b.x);
  r[5] = static_cast<__bf16>(b.y);
  r[6] = static_cast<__bf16>(b.z);
  r[7] = static_cast<__bf16>(b.w);
  return r;
}

// ---------- pass 1: node projections (dense MFMA GEMM, no gather) ----------
__global__ __launch_bounds__(512, 2) void proj_nodes(
    const float* __restrict__ zu, int NU, const float* __restrict__ zr, int NR,
    const float* __restrict__ W1, unsigned short* __restrict__ Hu,
    unsigned short* __restrict__ Hr) {
  // W1 bf16, B-fragment order: Bsw[((kc*4+nt)*64+lane)*8+j],
  //   k = kc*16 + (lane>>5)*8 + j, n = nt*32 + (lane&31). kc 0..7 = W1[:128]
  //   (user half), kc 8..15 = W1[128:] (recipe half).
  __shared__ unsigned short Bsw[32768];
  const int tid = threadIdx.x;
  {
    const int n = tid & 127;
    const int kh = tid >> 7;  // 0..3
    const int nt = n >> 5;
    const int nl = n & 31;
#pragma unroll 8
    for (int it = 0; it < 64; ++it) {
      const int k = (it << 2) + kh;
      const float w = W1[k * HDIM + n];
      const int kc = k >> 4;
      const int q = (k >> 3) & 1;
      const int j = k & 7;
      const int ln = (q << 5) | nl;
      Bsw[((((kc << 2) + nt) << 6) | ln) * 8 + j] = bf16_bits(w);
    }
  }
  __syncthreads();

  const int lane = tid & 63;
  const int wid = tid >> 6;  // 0..7
  const int m = lane & 31;
  const int half = lane >> 5;
  const int koff = half * 8;
  const int utiles = NU >> 5;          // full (NU % 32 == 0)
  const int rtiles = (NR + 31) >> 5;   // last may be partial
  const int ntiles = utiles + rtiles;
  const int wstride = gridDim.x * 8;

  for (int t = blockIdx.x * 8 + wid; t < ntiles; t += wstride) {
    const bool isU = t < utiles;
    const int base = isU ? (t << 5) : ((t - utiles) << 5);
    const int nmax = isU ? NU : NR;
    const bool full = (base + 32) <= nmax;
    int node = base + m;
    if (node >= nmax) node = nmax - 1;
    const float* src = (isU ? zu : zr) + (size_t)node * HDIM + koff;
    const int kc0 = isU ? 0 : 8;

    f32x16 acc[4];
#pragma unroll
    for (int nt = 0; nt < 4; ++nt) acc[nt] = (f32x16)0.0f;

#pragma unroll
    for (int kcl = 0; kcl < 8; ++kcl) {
      const float4* sa = (const float4*)(src + kcl * 16);
      const bf16x8 a = cvt8(sa[0], sa[1]);
#pragma unroll
      for (int nt = 0; nt < 4; ++nt) {
        const uint4* bp =
            (const uint4*)(Bsw + (((((kc0 + kcl) << 2) + nt) << 6) | lane) * 8);
        const bf16x8 bfr = __builtin_bit_cast(bf16x8, *bp);
        acc[nt] = __builtin_amdgcn_mfma_f32_32x32x16_bf16(a, bfr, acc[nt], 0, 0, 0);
      }
    }

    unsigned short* H = isU ? Hu : Hr;
    if (full) {
#pragma unroll
      for (int nt = 0; nt < 4; ++nt) {
#pragma unroll
        for (int r = 0; r < 16; ++r) {
          const int row = (r & 3) + ((r >> 2) << 3) + (half << 2);
          H[(size_t)(base + row) * HDIM + (nt << 5) + m] = bf16_bits(acc[nt][r]);
        }
      }
    } else {
#pragma unroll
      for (int nt = 0; nt < 4; ++nt) {
#pragma unroll
        for (int r = 0; r < 16; ++r) {
          const int row = (r & 3) + ((r >> 2) << 3) + (half << 2);
          const int nrow = base + row;
          if (nrow < nmax)
            H[(size_t)nrow * HDIM + (nt << 5) + m] = bf16_bits(acc[nt][r]);
        }
      }
    }
  }
}

// ---------- pass 2: gather + relu + dot(W2) ---------------------------------
static __device__ __forceinline__ float dot8(uint4 a, uint4 b,
                                             const float* b1c,
                                             const float* w2c) {
  const unsigned short* pa = (const unsigned short*)&a;
  const unsigned short* pb = (const unsigned short*)&b;
  float s = 0.f;
#pragma unroll
  for (int j = 0; j < 8; ++j) {
    const float h = bf2f(pa[j]) + bf2f(pb[j]) + b1c[j];
    s = fmaf(fmaxf(h, 0.f), w2c[j], s);
  }
  return s;
}

__global__ __launch_bounds__(256, 4) void edge_pass(
    const unsigned short* __restrict__ Hu, const unsigned short* __restrict__ Hr,
    const int* __restrict__ eidx, const float* __restrict__ b1,
    const float* __restrict__ W2, const float* __restrict__ b2,
    float* __restrict__ out, int E) {
  const int tid = threadIdx.x;
  const int lane = tid & 63;
  const int c = lane & 15;   // 16 B chunk within the 256 B row
  const int g = lane >> 4;   // quarter-wave group: 4 edges each
  const int wid = blockIdx.x * 4 + (tid >> 6);
  const int stride = gridDim.x * 4 * 16;  // 16 edges per wave per iteration

  float b1c[8], w2c[8];
#pragma unroll
  for (int j = 0; j < 8; ++j) {
    b1c[j] = b1[c * 8 + j];
    w2c[j] = W2[c * 8 + j];
  }
  const float b2v = b2[0];
  const int co = c * 8;  // column offset within the 128-col row

  int e = wid * 16 + g * 4;  // group's 4 edges (E % 16 == 0)
  if (e >= E) return;
  int4 iu = *(const int4*)(eidx + e);
  int4 ir = *(const int4*)(eidx + E + e);

  while (true) {
    const int en = e + stride;
    const bool more = en < E;
    const int ep = more ? en : e;

    const uint4 au0 = *(const uint4*)(Hu + (size_t)iu.x * HDIM + co);
    const uint4 ar0 = *(const uint4*)(Hr + (size_t)ir.x * HDIM + co);
    const uint4 au1 = *(const uint4*)(Hu + (size_t)iu.y * HDIM + co);
    const uint4 ar1 = *(const uint4*)(Hr + (size_t)ir.y * HDIM + co);
    const uint4 au2 = *(const uint4*)(Hu + (size_t)iu.z * HDIM + co);
    const uint4 ar2 = *(const uint4*)(Hr + (size_t)ir.z * HDIM + co);
    const uint4 au3 = *(const uint4*)(Hu + (size_t)iu.w * HDIM + co);
    const uint4 ar3 = *(const uint4*)(Hr + (size_t)ir.w * HDIM + co);

    const int4 niu = *(const int4*)(eidx + ep);
    const int4 nir = *(const int4*)(eidx + E + ep);

    float s0 = dot8(au0, ar0, b1c, w2c);
    float s1 = dot8(au1, ar1, b1c, w2c);
    float s2 = dot8(au2, ar2, b1c, w2c);
    float s3 = dot8(au3, ar3, b1c, w2c);
#pragma unroll
    for (int st = 1; st <= 8; st <<= 1) {
      s0 += __shfl_xor(s0, st);
      s1 += __shfl_xor(s1, st);
      s2 += __shfl_xor(s2, st);
      s3 += __shfl_xor(s3, st);
    }
    if (c == 0) {
      float4 o = make_float4(s0 + b2v, s1 + b2v, s2 + b2v, s3 + b2v);
      *(float4*)(out + e) = o;
    }
    if (!more) break;
    e = en;
    iu = niu;
    ir = nir;
  }
}

// ---------- fallback (R1 kernel, fp32 gathers, no workspace) ---------------
__global__ __launch_bounds__(256, 2) void edge_decoder_mfma(
    const float* __restrict__ zu, const float* __restrict__ zr,
    const int* __restrict__ eidx, const float* __restrict__ W1,
    const float* __restrict__ b1, const float* __restrict__ W2,
    const float* __restrict__ b2, float* __restrict__ out, int E) {
  __shared__ unsigned short Bsw[32768];
  const int tid = threadIdx.x;
  {
    const int n = tid & 127;
    const int kh = tid >> 7;
    const int nt = n >> 5;
    const int nl = n & 31;
#pragma unroll 8
    for (int it = 0; it < 128; ++it) {
      const int k = 2 * it + kh;
      const float w = W1[k * HDIM + n];
      const int kc = k >> 4;
      const int q = (k >> 3) & 1;
      const int j = k & 7;
      const int ln = (q << 5) | nl;
      Bsw[((((kc << 2) + nt) << 6) | ln) * 8 + j] = bf16_bits(w);
    }
  }
  __syncthreads();

  const int lane = tid & 63;
  const int wid = tid >> 6;
  const int m = lane & 31;
  const int half = lane >> 5;
  const int nsweep = E >> 6;
  const int wstride = gridDim.x * 4;

  float b1v[4], w2v[4];
#pragma unroll
  for (int nt = 0; nt < 4; ++nt) {
    b1v[nt] = b1[nt * 32 + m];
    w2v[nt] = W2[nt * 32 + m];
  }
  const float b2v = b2[0];
  const int koff = half * 8;

  for (int s = blockIdx.x * 4 + wid; s < nsweep; s += wstride) {
    const int e0 = s << 6;
    const int eA = e0 + m;
    const int eB = e0 + 32 + m;
    const float* puA = zu + (size_t)eidx[eA] * HDIM;
    const float* prA = zr + (size_t)eidx[E + eA] * HDIM;
    const float* puB = zu + (size_t)eidx[eB] * HDIM;
    const float* prB = zr + (size_t)eidx[E + eB] * HDIM;

    f32x16 acc[2][4];
#pragma unroll
    for (int mt = 0; mt < 2; ++mt)
#pragma unroll
      for (int nt = 0; nt < 4; ++nt) acc[mt][nt] = (f32x16)0.0f;

#pragma unroll
    for (int kc = 0; kc < 16; ++kc) {
      const float* srcA = (kc < 8) ? (puA + kc * 16 + koff) : (prA + (kc - 8) * 16 + koff);
      const float* srcB = (kc < 8) ? (puB + kc * 16 + koff) : (prB + (kc - 8) * 16 + koff);
      const float4* sa = (const float4*)srcA;
      const float4* sb = (const float4*)srcB;
      const bf16x8 a0 = cvt8(sa[0], sa[1]);
      const bf16x8 a1 = cvt8(sb[0], sb[1]);
#pragma unroll
      for (int nt = 0; nt < 4; ++nt) {
        const uint4* bp = (const uint4*)(Bsw + ((((kc << 2) + nt) << 6) | lane) * 8);
        const bf16x8 bfr = __builtin_bit_cast(bf16x8, *bp);
        acc[0][nt] = __builtin_amdgcn_mfma_f32_32x32x16_bf16(a0, bfr, acc[0][nt], 0, 0, 0);
        acc[1][nt] = __builtin_amdgcn_mfma_f32_32x32x16_bf16(a1, bfr, acc[1][nt], 0, 0, 0);
      }
    }

    float p0[16], p1[16];
#pragma unroll
    for (int r = 0; r < 16; ++r) { p0[r] = 0.f; p1[r] = 0.f; }
#pragma unroll
    for (int nt = 0; nt < 4; ++nt) {
#pragma unroll
      for (int r = 0; r < 16; ++r) {
        float h0 = fmaxf(acc[0][nt][r] + b1v[nt], 0.f);
        float h1 = fmaxf(acc[1][nt][r] + b1v[nt], 0.f);
        p0[r] = fmaf(h0, w2v[nt], p0[r]);
        p1[r] = fmaf(h1, w2v[nt], p1[r]);
      }
    }
#pragma unroll
    for (int st = 1; st <= 16; st <<= 1) {
#pragma unroll
      for (int r = 0; r < 16; ++r) {
        p0[r] += __shfl_xor(p0[r], st);
        p1[r] += __shfl_xor(p1[r], st);
      }
    }
    const int sel = lane & 15;
    const int mtw = (lane >> 4) & 1;
    float val = 0.f;
#pragma unroll
    for (int r = 0; r < 16; ++r) {
      const float cand = mtw ? p1[r] : p0[r];
      val = (sel == r) ? cand : val;
    }
    const int mrow = (sel & 3) + ((sel >> 2) << 3) + (half << 2);
    out[e0 + (mtw << 5) + mrow] = val + b2v;
  }
}

extern "C" void kernel_launch(void* const* d_in, const int* in_sizes, int n_in,
                              void* d_out, int out_size, void* d_ws,
                              size_t ws_size, hipStream_t stream) {
  const float* zu = (const float*)d_in[0];
  const float* zr = (const float*)d_in[1];
  const int* eidx = (const int*)d_in[2];
  const float* W1 = (const float*)d_in[3];
  const float* b1 = (const float*)d_in[4];
  const float* W2 = (const float*)d_in[5];
  const float* b2 = (const float*)d_in[6];
  float* out = (float*)d_out;
  const int nu = in_sizes[0];     // N_USER * 128
  const int nr = in_sizes[1];     // N_RECIPE * 128
  const int E = in_sizes[2] / 2;  // 1,000,000
  const int NU = nu / HDIM, NR = nr / HDIM;

  const size_t need = (size_t)(nu + nr) * sizeof(unsigned short);
  if (ws_size >= need && (E % 16) == 0) {
    unsigned short* Hu = (unsigned short*)d_ws;
    unsigned short* Hr = Hu + (size_t)nu;
    const int ntiles = (NU >> 5) + ((NR + 31) >> 5);
    const int pblocks = (ntiles + 7) / 8;  // one tile per wave
    hipLaunchKernelGGL(proj_nodes, dim3(pblocks), dim3(512), 0, stream,
                       zu, NU, zr, NR, W1, Hu, Hr);
    hipLaunchKernelGGL(edge_pass, dim3(2048), dim3(256), 0, stream,
                       Hu, Hr, eidx, b1, W2, b2, out, E);
  } else {
    hipLaunchKernelGGL(edge_decoder_mfma, dim3(512), dim3(256), 0, stream,
                       zu, zr, eidx, W1, b1, W2, b2, out, E);
  }
}

// Round 5
// 196.431 us; speedup vs baseline: 1.0061x; 1.0061x over previous
//
#include <hip/hip_runtime.h>
#include <hip/hip_bf16.h>

// EdgeDecoder: out[e] = relu(concat(zu[row[e]], zr[col[e]]) @ W1 + b1) @ W2 + b2
// R5: two-pass factorization (proj_nodes MFMA -> Hu/Hr bf16 in d_ws;
// edge_pass gather+relu+dot), occupancy/latency tuning:
//   - edge_pass: 6144-block grid-stride (3x wave oversubscription; R4's exact
//     8192-wave launch never exceeded 40-64% occupancy). No manual index
//     prefetch (lower VGPR, waves hide latency instead).
//   - proj_nodes: blocks specialize to user- or recipe-half of W1 -> 32 KB
//     LDS -> 4 blocks/CU (32 waves/CU vs 16). One 32-row tile per wave.

#define HDIM 128

typedef __attribute__((ext_vector_type(8))) __bf16 bf16x8;
typedef __attribute__((ext_vector_type(16))) float f32x16;

static __device__ __forceinline__ unsigned short bf16_bits(float x) {
  return __builtin_bit_cast(unsigned short, static_cast<__bf16>(x));
}

static __device__ __forceinline__ float bf2f(unsigned short u) {
  return __builtin_bit_cast(float, ((unsigned int)u) << 16);
}

static __device__ __forceinline__ bf16x8 cvt8(float4 a, float4 b) {
  bf16x8 r;
  r[0] = static_cast<__bf16>(a.x);
  r[1] = static_cast<__bf16>(a.y);
  r[2] = static_cast<__bf16>(a.z);
  r[3] = static_cast<__bf16>(a.w);
  r[4] = static_cast<__bf16>(b.x);
  r[5] = static_cast<__bf16>(b.y);
  r[6] = static_cast<__bf16>(b.z);
  r[7] = static_cast<__bf16>(b.w);
  return r;
}

// ---------- pass 1: node projections (dense MFMA GEMM, no gather) ----------
// Blocks [0, UB) handle z_user tiles with W1 rows [0,128); blocks [UB, ...)
// handle z_recipe tiles with W1 rows [128,256). Each stages only its 128x128
// half of W1 into 32 KB LDS (same verified B-fragment layout, kc local 0..7).
__global__ __launch_bounds__(512, 4) void proj_nodes(
    const float* __restrict__ zu, int NU, const float* __restrict__ zr, int NR,
    const float* __restrict__ W1, unsigned short* __restrict__ Hu,
    unsigned short* __restrict__ Hr, int UB) {
  __shared__ unsigned short Bsw[16384];  // 32 KB: one half of W1
  const int tid = threadIdx.x;
  const bool isU = (int)blockIdx.x < UB;
  const int kbase = isU ? 0 : HDIM;  // W1 row offset for this half
  {
    const int n = tid & 127;
    const int kh = tid >> 7;  // 0..3
    const int nt = n >> 5;
    const int nl = n & 31;
#pragma unroll 8
    for (int it = 0; it < 32; ++it) {
      const int k = (it << 2) + kh;  // local k 0..127
      const float w = W1[(kbase + k) * HDIM + n];
      const int kc = k >> 4;         // local 0..7
      const int q = (k >> 3) & 1;
      const int j = k & 7;
      const int ln = (q << 5) | nl;
      Bsw[((((kc << 2) + nt) << 6) | ln) * 8 + j] = bf16_bits(w);
    }
  }
  __syncthreads();

  const int lane = tid & 63;
  const int wid = tid >> 6;  // 0..7
  const int m = lane & 31;
  const int half = lane >> 5;
  const int koff = half * 8;

  const int t = (isU ? (int)blockIdx.x : (int)blockIdx.x - UB) * 8 + wid;
  const int ntile = isU ? (NU + 31) >> 5 : (NR + 31) >> 5;
  if (t >= ntile) return;

  const int nmax = isU ? NU : NR;
  const int base = t << 5;
  const bool full = (base + 32) <= nmax;
  int node = base + m;
  if (node >= nmax) node = nmax - 1;
  const float* src = (isU ? zu : zr) + (size_t)node * HDIM + koff;

  f32x16 acc[4];
#pragma unroll
  for (int nt = 0; nt < 4; ++nt) acc[nt] = (f32x16)0.0f;

#pragma unroll
  for (int kcl = 0; kcl < 8; ++kcl) {
    const float4* sa = (const float4*)(src + kcl * 16);
    const bf16x8 a = cvt8(sa[0], sa[1]);
#pragma unroll
    for (int nt = 0; nt < 4; ++nt) {
      const uint4* bp =
          (const uint4*)(Bsw + ((((kcl << 2) + nt) << 6) | lane) * 8);
      const bf16x8 bfr = __builtin_bit_cast(bf16x8, *bp);
      acc[nt] = __builtin_amdgcn_mfma_f32_32x32x16_bf16(a, bfr, acc[nt], 0, 0, 0);
    }
  }

  unsigned short* H = isU ? Hu : Hr;
  if (full) {
#pragma unroll
    for (int nt = 0; nt < 4; ++nt) {
#pragma unroll
      for (int r = 0; r < 16; ++r) {
        const int row = (r & 3) + ((r >> 2) << 3) + (half << 2);
        H[(size_t)(base + row) * HDIM + (nt << 5) + m] = bf16_bits(acc[nt][r]);
      }
    }
  } else {
#pragma unroll
    for (int nt = 0; nt < 4; ++nt) {
#pragma unroll
      for (int r = 0; r < 16; ++r) {
        const int row = (r & 3) + ((r >> 2) << 3) + (half << 2);
        const int nrow = base + row;
        if (nrow < nmax)
          H[(size_t)nrow * HDIM + (nt << 5) + m] = bf16_bits(acc[nt][r]);
      }
    }
  }
}

// ---------- pass 2: gather + relu + dot(W2) ---------------------------------
static __device__ __forceinline__ float dot8(uint4 a, uint4 b,
                                             const float* b1c,
                                             const float* w2c) {
  const unsigned short* pa = (const unsigned short*)&a;
  const unsigned short* pb = (const unsigned short*)&b;
  float s = 0.f;
#pragma unroll
  for (int j = 0; j < 8; ++j) {
    const float h = bf2f(pa[j]) + bf2f(pb[j]) + b1c[j];
    s = fmaf(fmaxf(h, 0.f), w2c[j], s);
  }
  return s;
}

__global__ __launch_bounds__(256, 4) void edge_pass(
    const unsigned short* __restrict__ Hu, const unsigned short* __restrict__ Hr,
    const int* __restrict__ eidx, const float* __restrict__ b1,
    const float* __restrict__ W2, const float* __restrict__ b2,
    float* __restrict__ out, int E) {
  const int tid = threadIdx.x;
  const int lane = tid & 63;
  const int c = lane & 15;   // 16 B chunk within the 256 B row
  const int g = lane >> 4;   // quarter-wave group: 4 edges each
  const int wid = blockIdx.x * 4 + (tid >> 6);
  const int stride = gridDim.x * 4 * 16;  // 16 edges per wave per iteration

  float b1c[8], w2c[8];
#pragma unroll
  for (int j = 0; j < 8; ++j) {
    b1c[j] = b1[c * 8 + j];
    w2c[j] = W2[c * 8 + j];
  }
  const float b2v = b2[0];
  const int co = c * 8;  // column offset within the 128-col row

  for (int e = wid * 16 + g * 4; e < E; e += stride) {  // E % 16 == 0
    const int4 iu = *(const int4*)(eidx + e);
    const int4 ir = *(const int4*)(eidx + E + e);

    const uint4 au0 = *(const uint4*)(Hu + (size_t)iu.x * HDIM + co);
    const uint4 ar0 = *(const uint4*)(Hr + (size_t)ir.x * HDIM + co);
    const uint4 au1 = *(const uint4*)(Hu + (size_t)iu.y * HDIM + co);
    const uint4 ar1 = *(const uint4*)(Hr + (size_t)ir.y * HDIM + co);
    const uint4 au2 = *(const uint4*)(Hu + (size_t)iu.z * HDIM + co);
    const uint4 ar2 = *(const uint4*)(Hr + (size_t)ir.z * HDIM + co);
    const uint4 au3 = *(const uint4*)(Hu + (size_t)iu.w * HDIM + co);
    const uint4 ar3 = *(const uint4*)(Hr + (size_t)ir.w * HDIM + co);

    float s0 = dot8(au0, ar0, b1c, w2c);
    float s1 = dot8(au1, ar1, b1c, w2c);
    float s2 = dot8(au2, ar2, b1c, w2c);
    float s3 = dot8(au3, ar3, b1c, w2c);
#pragma unroll
    for (int st = 1; st <= 8; st <<= 1) {
      s0 += __shfl_xor(s0, st);
      s1 += __shfl_xor(s1, st);
      s2 += __shfl_xor(s2, st);
      s3 += __shfl_xor(s3, st);
    }
    if (c == 0) {
      float4 o = make_float4(s0 + b2v, s1 + b2v, s2 + b2v, s3 + b2v);
      *(float4*)(out + e) = o;
    }
  }
}

// ---------- fallback (R1 kernel, fp32 gathers, no workspace) ---------------
__global__ __launch_bounds__(256, 2) void edge_decoder_mfma(
    const float* __restrict__ zu, const float* __restrict__ zr,
    const int* __restrict__ eidx, const float* __restrict__ W1,
    const float* __restrict__ b1, const float* __restrict__ W2,
    const float* __restrict__ b2, float* __restrict__ out, int E) {
  __shared__ unsigned short Bsw[32768];
  const int tid = threadIdx.x;
  {
    const int n = tid & 127;
    const int kh = tid >> 7;
    const int nt = n >> 5;
    const int nl = n & 31;
#pragma unroll 8
    for (int it = 0; it < 128; ++it) {
      const int k = 2 * it + kh;
      const float w = W1[k * HDIM + n];
      const int kc = k >> 4;
      const int q = (k >> 3) & 1;
      const int j = k & 7;
      const int ln = (q << 5) | nl;
      Bsw[((((kc << 2) + nt) << 6) | ln) * 8 + j] = bf16_bits(w);
    }
  }
  __syncthreads();

  const int lane = tid & 63;
  const int wid = tid >> 6;
  const int m = lane & 31;
  const int half = lane >> 5;
  const int nsweep = E >> 6;
  const int wstride = gridDim.x * 4;

  float b1v[4], w2v[4];
#pragma unroll
  for (int nt = 0; nt < 4; ++nt) {
    b1v[nt] = b1[nt * 32 + m];
    w2v[nt] = W2[nt * 32 + m];
  }
  const float b2v = b2[0];
  const int koff = half * 8;

  for (int s = blockIdx.x * 4 + wid; s < nsweep; s += wstride) {
    const int e0 = s << 6;
    const int eA = e0 + m;
    const int eB = e0 + 32 + m;
    const float* puA = zu + (size_t)eidx[eA] * HDIM;
    const float* prA = zr + (size_t)eidx[E + eA] * HDIM;
    const float* puB = zu + (size_t)eidx[eB] * HDIM;
    const float* prB = zr + (size_t)eidx[E + eB] * HDIM;

    f32x16 acc[2][4];
#pragma unroll
    for (int mt = 0; mt < 2; ++mt)
#pragma unroll
      for (int nt = 0; nt < 4; ++nt) acc[mt][nt] = (f32x16)0.0f;

#pragma unroll
    for (int kc = 0; kc < 16; ++kc) {
      const float* srcA = (kc < 8) ? (puA + kc * 16 + koff) : (prA + (kc - 8) * 16 + koff);
      const float* srcB = (kc < 8) ? (puB + kc * 16 + koff) : (prB + (kc - 8) * 16 + koff);
      const float4* sa = (const float4*)srcA;
      const float4* sb = (const float4*)srcB;
      const bf16x8 a0 = cvt8(sa[0], sa[1]);
      const bf16x8 a1 = cvt8(sb[0], sb[1]);
#pragma unroll
      for (int nt = 0; nt < 4; ++nt) {
        const uint4* bp = (const uint4*)(Bsw + ((((kc << 2) + nt) << 6) | lane) * 8);
        const bf16x8 bfr = __builtin_bit_cast(bf16x8, *bp);
        acc[0][nt] = __builtin_amdgcn_mfma_f32_32x32x16_bf16(a0, bfr, acc[0][nt], 0, 0, 0);
        acc[1][nt] = __builtin_amdgcn_mfma_f32_32x32x16_bf16(a1, bfr, acc[1][nt], 0, 0, 0);
      }
    }

    float p0[16], p1[16];
#pragma unroll
    for (int r = 0; r < 16; ++r) { p0[r] = 0.f; p1[r] = 0.f; }
#pragma unroll
    for (int nt = 0; nt < 4; ++nt) {
#pragma unroll
      for (int r = 0; r < 16; ++r) {
        float h0 = fmaxf(acc[0][nt][r] + b1v[nt], 0.f);
        float h1 = fmaxf(acc[1][nt][r] + b1v[nt], 0.f);
        p0[r] = fmaf(h0, w2v[nt], p0[r]);
        p1[r] = fmaf(h1, w2v[nt], p1[r]);
      }
    }
#pragma unroll
    for (int st = 1; st <= 16; st <<= 1) {
#pragma unroll
      for (int r = 0; r < 16; ++r) {
        p0[r] += __shfl_xor(p0[r], st);
        p1[r] += __shfl_xor(p1[r], st);
      }
    }
    const int sel = lane & 15;
    const int mtw = (lane >> 4) & 1;
    float val = 0.f;
#pragma unroll
    for (int r = 0; r < 16; ++r) {
      const float cand = mtw ? p1[r] : p0[r];
      val = (sel == r) ? cand : val;
    }
    const int mrow = (sel & 3) + ((sel >> 2) << 3) + (half << 2);
    out[e0 + (mtw << 5) + mrow] = val + b2v;
  }
}

extern "C" void kernel_launch(void* const* d_in, const int* in_sizes, int n_in,
                              void* d_out, int out_size, void* d_ws,
                              size_t ws_size, hipStream_t stream) {
  const float* zu = (const float*)d_in[0];
  const float* zr = (const float*)d_in[1];
  const int* eidx = (const int*)d_in[2];
  const float* W1 = (const float*)d_in[3];
  const float* b1 = (const float*)d_in[4];
  const float* W2 = (const float*)d_in[5];
  const float* b2 = (const float*)d_in[6];
  float* out = (float*)d_out;
  const int nu = in_sizes[0];     // N_USER * 128
  const int nr = in_sizes[1];     // N_RECIPE * 128
  const int E = in_sizes[2] / 2;  // 1,000,000
  const int NU = nu / HDIM, NR = nr / HDIM;

  const size_t need = (size_t)(nu + nr) * sizeof(unsigned short);
  if (ws_size >= need && (E % 16) == 0) {
    unsigned short* Hu = (unsigned short*)d_ws;
    unsigned short* Hr = Hu + (size_t)nu;
    const int utiles = (NU + 31) >> 5;
    const int rtiles = (NR + 31) >> 5;
    const int UB = (utiles + 7) / 8;           // user blocks (8 tiles each)
    const int RB = (rtiles + 7) / 8;           // recipe blocks
    hipLaunchKernelGGL(proj_nodes, dim3(UB + RB), dim3(512), 0, stream,
                       zu, NU, zr, NR, W1, Hu, Hr, UB);
    hipLaunchKernelGGL(edge_pass, dim3(6144), dim3(256), 0, stream,
                       Hu, Hr, eidx, b1, W2, b2, out, E);
  } else {
    hipLaunchKernelGGL(edge_decoder_mfma, dim3(512), dim3(256), 0, stream,
                       zu, zr, eidx, W1, b1, W2, b2, out, E);
  }
}